// Round 1
// baseline (1487.909 us; speedup 1.0000x reference)
//
#include <hip/hip_runtime.h>
#include <stdint.h>

typedef __bf16 bf16_t;
typedef _Float16 fp16_t;
typedef bf16_t bf16x8 __attribute__((ext_vector_type(8)));
typedef float f32x4 __attribute__((ext_vector_type(4)));

#define LOG2E 1.44269504088896340736f

__device__ __forceinline__ float sigm(float x) {
    return __builtin_amdgcn_rcpf(1.f + __builtin_amdgcn_exp2f(-LOG2E * x));
}
__device__ __forceinline__ float tanh_(float x) {
    // tanh(x) = 1 - 2/(exp(2x)+1); overflow-safe (exp2->inf -> rcp->0 -> 1)
    return 1.f - 2.f * __builtin_amdgcn_rcpf(1.f + __builtin_amdgcn_exp2f((2.f * LOG2E) * x));
}

// ---------------------------------------------------------------------------
// Kernel 1: fold fuse_W2@fuse_W1 into a single 340-vector + scalar
// ---------------------------------------------------------------------------
__global__ void prep_fuse(const float* __restrict__ W1, const float* __restrict__ b1,
                          const float* __restrict__ W2, const float* __restrict__ b2,
                          float* __restrict__ v) {
    int u = threadIdx.x;
    if (u < 340) {
        float s = 0.f;
        for (int j = 0; j < 64; j++) s += W2[j] * W1[j * 340 + u];
        v[u] = s;
    } else if (u == 340) {
        float s = 0.f;
        for (int j = 0; j < 64; j++) s += W2[j] * b1[j];
        v[340] = s + b2[0];
    }
}

// ---------------------------------------------------------------------------
// Kernel 2: input GEMMs  xg[row][n] = sum_k x[row][k]*W_ih[n][k] + b_ih[n]
// BM=64, BN=N4 (<=512), BK=32. Split-bf16 on A (x = hi + lo) for accuracy.
// ---------------------------------------------------------------------------
struct ModGemm {
    const float* x; const float* w; const float* bih; fp16_t* xg;
    int D; int N4; int KB;
};
struct GemmArgs { ModGemm m[4]; };

__global__ __launch_bounds__(512) void gemm_all(GemmArgs ga) {
    __shared__ bf16_t sAh[64 * 40];
    __shared__ bf16_t sAl[64 * 40];
    __shared__ bf16_t sB[512 * 40];
    const ModGemm mg = ga.m[blockIdx.z];
    const int tid = threadIdx.x;
    const int l = tid & 63, w = tid >> 6;
    const int lm = l & 15, q = l >> 4;
    const int bm = blockIdx.x;
    const int NTB = mg.N4 >> 4;   // N tiles (<=32)
    const int D = mg.D;

    f32x4 acc[4][4];
#pragma unroll
    for (int a = 0; a < 4; a++)
#pragma unroll
        for (int b = 0; b < 4; b++) acc[a][b] = 0.f;

    for (int kb = 0; kb < mg.KB; kb++) {
        const int k0b = kb << 5;
        // ---- stage A (x): 64 rows x 32, hi+lo split
        for (int i8 = tid; i8 < 64 * 4; i8 += 512) {
            int r = i8 >> 2, c = (i8 & 3) << 3;
            long grow = (long)(bm << 6) + r;
            union { bf16_t e[8]; bf16x8 v; } uh, ul;
            if (k0b + c + 8 <= D) {
                const float* src = mg.x + grow * D + k0b + c;
#pragma unroll
                for (int j = 0; j < 8; j += 2) {
                    float2 v2 = *(const float2*)(src + j);
                    bf16_t h0 = (bf16_t)v2.x, h1 = (bf16_t)v2.y;
                    uh.e[j] = h0; uh.e[j + 1] = h1;
                    ul.e[j] = (bf16_t)(v2.x - (float)h0);
                    ul.e[j + 1] = (bf16_t)(v2.y - (float)h1);
                }
            } else {
#pragma unroll
                for (int j = 0; j < 8; j++) {
                    int k = k0b + c + j;
                    float fv = (k < D) ? mg.x[grow * D + k] : 0.f;
                    bf16_t h0 = (bf16_t)fv;
                    uh.e[j] = h0; ul.e[j] = (bf16_t)(fv - (float)h0);
                }
            }
            *(bf16x8*)&sAh[r * 40 + c] = uh.v;
            *(bf16x8*)&sAl[r * 40 + c] = ul.v;
        }
        // ---- stage B (W_ih): N4 rows x 32
        for (int i8 = tid; i8 < (NTB << 6); i8 += 512) {
            int r = i8 >> 2, c = (i8 & 3) << 3;
            union { bf16_t e[8]; bf16x8 v; } ub;
            if (k0b + c + 8 <= D) {
                const float* src = mg.w + (long)r * D + k0b + c;
#pragma unroll
                for (int j = 0; j < 8; j += 2) {
                    float2 v2 = *(const float2*)(src + j);
                    ub.e[j] = (bf16_t)v2.x; ub.e[j + 1] = (bf16_t)v2.y;
                }
            } else {
#pragma unroll
                for (int j = 0; j < 8; j++) {
                    int k = k0b + c + j;
                    ub.e[j] = (k < D) ? (bf16_t)mg.w[(long)r * D + k] : (bf16_t)0.f;
                }
            }
            *(bf16x8*)&sB[r * 40 + c] = ub.v;
        }
        __syncthreads();
        bf16x8 afh[4], afl[4];
#pragma unroll
        for (int mt = 0; mt < 4; mt++) {
            afh[mt] = *(const bf16x8*)&sAh[(mt * 16 + lm) * 40 + (q << 3)];
            afl[mt] = *(const bf16x8*)&sAl[(mt * 16 + lm) * 40 + (q << 3)];
        }
#pragma unroll
        for (int k4 = 0; k4 < 4; k4++) {
            int nt = w + (k4 << 3);
            if (nt < NTB) {
                bf16x8 bfr = *(const bf16x8*)&sB[(nt * 16 + lm) * 40 + (q << 3)];
#pragma unroll
                for (int mt = 0; mt < 4; mt++) {
                    acc[k4][mt] = __builtin_amdgcn_mfma_f32_16x16x32_bf16(afh[mt], bfr, acc[k4][mt], 0, 0, 0);
                    acc[k4][mt] = __builtin_amdgcn_mfma_f32_16x16x32_bf16(afl[mt], bfr, acc[k4][mt], 0, 0, 0);
                }
            }
        }
        __syncthreads();
    }
    // ---- epilogue: + bias, store fp16
#pragma unroll
    for (int k4 = 0; k4 < 4; k4++) {
        int nt = w + (k4 << 3);
        if (nt >= NTB) continue;
        int col = nt * 16 + lm;
        float bias = mg.bih[col];
#pragma unroll
        for (int mt = 0; mt < 4; mt++) {
#pragma unroll
            for (int r = 0; r < 4; r++) {
                long row = (long)(bm << 6) + mt * 16 + (q << 2) + r;
                mg.xg[row * mg.N4 + col] = (fp16_t)(acc[k4][mt][r] + bias);
            }
        }
    }
}

// ---------------------------------------------------------------------------
// Kernel 3: recurrent scan. 16 blocks = 4 mods x 4 batch-groups of 16.
// ---------------------------------------------------------------------------
struct ModRec {
    const float* whh; const float* bhh; const int* present; const fp16_t* xg;
    int N4; int voff;
};
struct RecArgs {
    ModRec m[4];
    const float* vvec;
    float* s_out;   // [4][64][512]
};

template <int H>
__device__ void rec_mfma(const ModRec M, int grp, float* __restrict__ s_out,
                         const float* __restrict__ vvec,
                         float* presf, bf16_t* hb, float* sred, int tid) {
    constexpr int KT = H / 32;    // K tiles
    constexpr int TPG = H / 16;   // tiles per gate == active waves
    constexpr int Hp = H + 8;     // padded LDS stride for h
    const int N4 = 4 * H;
    const int l = tid & 63, w = tid >> 6;
    const int lm = l & 15, q = l >> 4;
    const int b0 = grp << 4;
    const bool act = (w < TPG);

    for (int i = tid; i < 16 * Hp; i += 512) hb[i] = (bf16_t)0.f;
    for (int i = tid; i < 16 * 512; i += 512) {
        int bl = i >> 9, tt = i & 511;
        presf[i] = (float)M.present[((b0 + bl) << 9) + tt];
    }

    bf16x8 wf[4][KT];
    float bhh_r[4] = {0, 0, 0, 0};
    int colg[4] = {0, 0, 0, 0};
    float vv = 0.f;
    if (act) {
#pragma unroll
        for (int g = 0; g < 4; g++) {
            int n = ((w + TPG * g) << 4) + lm;   // row of W_hh / col of xg
            colg[g] = n;
            bhh_r[g] = M.bhh[n];
#pragma unroll
            for (int kt = 0; kt < KT; kt++) {
                int k = (kt << 5) + (q << 3);
                const float* srcp = M.whh + (long)n * H + k;
                float4 f0 = *(const float4*)(srcp);
                float4 f1 = *(const float4*)(srcp + 4);
                union { bf16_t e[8]; bf16x8 v; } u;
                u.e[0] = (bf16_t)f0.x; u.e[1] = (bf16_t)f0.y;
                u.e[2] = (bf16_t)f0.z; u.e[3] = (bf16_t)f0.w;
                u.e[4] = (bf16_t)f1.x; u.e[5] = (bf16_t)f1.y;
                u.e[6] = (bf16_t)f1.z; u.e[7] = (bf16_t)f1.w;
                wf[g][kt] = u.v;
            }
        }
        vv = vvec[M.voff + (w << 4) + lm];
    }
    long rowbase[4];
#pragma unroll
    for (int r = 0; r < 4; r++) rowbase[r] = (long)((b0 + (q << 2) + r) << 9) * N4;

    float h_st[4] = {0, 0, 0, 0};
    float c_st[4] = {0, 0, 0, 0};
    __syncthreads();

    for (int t = 0; t < 512; t++) {
        f32x4 accv[4];
        float cr[4] = {0, 0, 0, 0};
        if (act) {
            bf16x8 af[KT];
#pragma unroll
            for (int kt = 0; kt < KT; kt++)
                af[kt] = *(const bf16x8*)&hb[lm * Hp + (kt << 5) + (q << 3)];
#pragma unroll
            for (int g = 0; g < 4; g++)
#pragma unroll
                for (int r = 0; r < 4; r++)
                    accv[g][r] = (float)M.xg[rowbase[r] + (long)t * N4 + colg[g]] + bhh_r[g];
#pragma unroll
            for (int kt = 0; kt < KT; kt++)
#pragma unroll
                for (int g = 0; g < 4; g++)
                    accv[g] = __builtin_amdgcn_mfma_f32_16x16x32_bf16(af[kt], wf[g][kt], accv[g], 0, 0, 0);
#pragma unroll
            for (int r = 0; r < 4; r++) {
                float gi = sigm(accv[0][r]);
                float gf = sigm(accv[1][r]);
                float gg = tanh_(accv[2][r]);
                float go = sigm(accv[3][r]);
                float cn = gf * c_st[r] + gi * gg;
                float hn = go * tanh_(cn);
                float p = presf[((q << 2) + r) * 512 + t];
                bool pb = (p != 0.f);
                float h2 = pb ? hn : h_st[r];
                float c2 = pb ? cn : c_st[r];
                h_st[r] = h2; c_st[r] = c2;
                cr[r] = h2 * vv;
            }
#pragma unroll
            for (int r = 0; r < 4; r++) {
                cr[r] += __shfl_xor(cr[r], 1);
                cr[r] += __shfl_xor(cr[r], 2);
                cr[r] += __shfl_xor(cr[r], 4);
                cr[r] += __shfl_xor(cr[r], 8);
            }
        }
        __syncthreads();   // all h reads of this step done
        if (act) {
            if (lm == 0) {
#pragma unroll
                for (int r = 0; r < 4; r++) sred[(w << 4) + (q << 2) + r] = cr[r];
            }
            int ucol = (w << 4) + lm;
#pragma unroll
            for (int r = 0; r < 4; r++) hb[((q << 2) + r) * Hp + ucol] = (bf16_t)h_st[r];
        }
        __syncthreads();
        if (tid < 16) {
            float s = 0.f;
#pragma unroll
            for (int ww = 0; ww < TPG; ww++) s += sred[(ww << 4) + tid];
            s_out[((b0 + tid) << 9) + t] = s;
        }
    }
}

// Emotient (H=20): full-fp32 VALU path, weights in registers.
__device__ void rec_emot(const ModRec M, int grp, float* __restrict__ s_out,
                         const float* __restrict__ vvec,
                         float* presf, float* gbuf /*16*81*/, float* he /*16*21*/, int tid) {
    const int b0 = grp << 4;
    for (int i = tid; i < 16 * 21; i += 512) he[i] = 0.f;
    for (int i = tid; i < 16 * 512; i += 512) {
        int bl = i >> 9, tt = i & 511;
        presf[i] = (float)M.present[((b0 + bl) << 9) + tt];
    }
    const int bl = tid >> 5;       // batch-local 0..15
    const int j0 = tid & 31;       // gate-row base
    const bool has2 = (j0 < 16);
    float wr0[20], wr1[20], wr2[20];
#pragma unroll
    for (int k = 0; k < 20; k++) {
        wr0[k] = M.whh[j0 * 20 + k];
        wr1[k] = M.whh[(j0 + 32) * 20 + k];
        wr2[k] = has2 ? M.whh[(j0 + 64) * 20 + k] : 0.f;
    }
    const float bh0 = M.bhh[j0];
    const float bh1 = M.bhh[j0 + 32];
    const float bh2 = has2 ? M.bhh[j0 + 64] : 0.f;
    const int b2 = tid / 20, u2 = tid % 20;
    const bool p2 = (tid < 320);
    const float vv2 = p2 ? vvec[M.voff + u2] : 0.f;
    float c_st = 0.f, h_st = 0.f;
    const long xrow = (long)((b0 + bl) << 9);
    __syncthreads();

    for (int t = 0; t < 512; t++) {
        {   // phase 1: gate pre-activations
            long xbase = (xrow + t) * 80;
            float g0 = (float)M.xg[xbase + j0] + bh0;
            float g1 = (float)M.xg[xbase + j0 + 32] + bh1;
            float g2 = has2 ? ((float)M.xg[xbase + j0 + 64] + bh2) : 0.f;
#pragma unroll
            for (int k = 0; k < 20; k++) {
                float hv = he[bl * 21 + k];
                g0 += wr0[k] * hv; g1 += wr1[k] * hv; g2 += wr2[k] * hv;
            }
            gbuf[bl * 81 + j0] = g0;
            gbuf[bl * 81 + j0 + 32] = g1;
            if (has2) gbuf[bl * 81 + j0 + 64] = g2;
        }
        __syncthreads();
        if (p2) {   // phase 2: cell update (one (b,u) per thread)
            float gi = sigm(gbuf[b2 * 81 + u2]);
            float gf = sigm(gbuf[b2 * 81 + u2 + 20]);
            float gg = tanh_(gbuf[b2 * 81 + u2 + 40]);
            float go = sigm(gbuf[b2 * 81 + u2 + 60]);
            float cn = gf * c_st + gi * gg;
            float hn = go * tanh_(cn);
            float p = presf[b2 * 512 + t];
            bool pb = (p != 0.f);
            h_st = pb ? hn : h_st;
            c_st = pb ? cn : c_st;
            he[b2 * 21 + u2] = h_st;
        }
        __syncthreads();
        if (tid < 16) {
            float s = 0.f;
#pragma unroll
            for (int u = 0; u < 20; u++) s += he[tid * 21 + u] * vvec[M.voff + u];
            s_out[((b0 + tid) << 9) + t] = s;
        }
        (void)vv2;
    }
}

__global__ __launch_bounds__(512) void rec_all(RecArgs ra) {
    __shared__ float presf[16 * 512];     // 32 KB
    __shared__ bf16_t hb[16 * 136];       // h (bf16, padded stride)
    __shared__ float sred[8 * 16];
    __shared__ float gbuf[16 * 81];
    __shared__ float he[16 * 21];
    const int tid = threadIdx.x;
    const int bid = blockIdx.x;
    const int mi = bid >> 2, grp = bid & 3;   // 0=L,1=E,2=A,3=I
    const ModRec M = ra.m[mi];
    float* s_out = ra.s_out + (long)mi * (64 * 512);
    if (mi == 1)      rec_emot(M, grp, s_out, ra.vvec, presf, gbuf, he, tid);
    else if (mi == 2) rec_mfma<64>(M, grp, s_out, ra.vvec, presf, hb, sred, tid);
    else              rec_mfma<128>(M, grp, s_out, ra.vvec, presf, hb, sred, tid);
}

// ---------------------------------------------------------------------------
// Kernel 4: out = mask * (sum_m s_m + c0)
// ---------------------------------------------------------------------------
__global__ void fuse_out(const float* __restrict__ sp, const float* __restrict__ v,
                         const float* __restrict__ masks, float* __restrict__ out) {
    int i = threadIdx.x + blockIdx.x * 256;
    float c0 = v[340];
    float s = sp[i] + sp[32768 + i] + sp[65536 + i] + sp[98304 + i];
    out[i] = masks[i] * (s + c0);
}

// ---------------------------------------------------------------------------
extern "C" void kernel_launch(void* const* d_in, const int* in_sizes, int n_in,
                              void* d_out, int out_size, void* d_ws, size_t ws_size,
                              hipStream_t stream) {
    const float* xL = (const float*)d_in[0];
    const int*   pL = (const int*)d_in[1];
    const float* WihL = (const float*)d_in[2];
    const float* WhhL = (const float*)d_in[3];
    const float* bihL = (const float*)d_in[4];
    const float* bhhL = (const float*)d_in[5];
    const float* xE = (const float*)d_in[6];
    const int*   pE = (const int*)d_in[7];
    const float* WihE = (const float*)d_in[8];
    const float* WhhE = (const float*)d_in[9];
    const float* bihE = (const float*)d_in[10];
    const float* bhhE = (const float*)d_in[11];
    const float* xA = (const float*)d_in[12];
    const int*   pA = (const int*)d_in[13];
    const float* WihA = (const float*)d_in[14];
    const float* WhhA = (const float*)d_in[15];
    const float* bihA = (const float*)d_in[16];
    const float* bhhA = (const float*)d_in[17];
    const float* xI = (const float*)d_in[18];
    const int*   pI = (const int*)d_in[19];
    const float* WihI = (const float*)d_in[20];
    const float* WhhI = (const float*)d_in[21];
    const float* bihI = (const float*)d_in[22];
    const float* bhhI = (const float*)d_in[23];
    const float* masks = (const float*)d_in[25];
    const float* fW1 = (const float*)d_in[26];
    const float* fb1 = (const float*)d_in[27];
    const float* fW2 = (const float*)d_in[28];
    const float* fb2 = (const float*)d_in[29];

    char* ws = (char*)d_ws;
    float* v     = (float*)ws;                       // 341 floats
    float* spart = (float*)(ws + (64 << 10));        // 4*64*512 floats
    fp16_t* xgL = (fp16_t*)(ws + (1 << 20));
    fp16_t* xgE = xgL + (size_t)32768 * 512;
    fp16_t* xgA = xgE + (size_t)32768 * 80;
    fp16_t* xgI = xgA + (size_t)32768 * 256;

    prep_fuse<<<dim3(1), dim3(512), 0, stream>>>(fW1, fb1, fW2, fb2, v);

    GemmArgs ga;
    ga.m[0] = {xL, WihL, bihL, xgL, 300,  512, 10};
    ga.m[1] = {xE, WihE, bihE, xgE, 30,   80,  1};
    ga.m[2] = {xA, WihA, bihA, xgA, 88,   256, 3};
    ga.m[3] = {xI, WihI, bihI, xgI, 1000, 512, 32};
    gemm_all<<<dim3(512, 1, 4), dim3(512), 0, stream>>>(ga);

    RecArgs ra;
    ra.m[0] = {WhhL, bhhL, pL, xgL, 512, 0};
    ra.m[1] = {WhhE, bhhE, pE, xgE, 80,  128};
    ra.m[2] = {WhhA, bhhA, pA, xgA, 256, 148};
    ra.m[3] = {WhhI, bhhI, pI, xgI, 512, 212};
    ra.vvec = v;
    ra.s_out = spart;
    rec_all<<<dim3(16), dim3(512), 0, stream>>>(ra);

    fuse_out<<<dim3(128), dim3(256), 0, stream>>>(spart, v, masks, (float*)d_out);
}

// Round 2
// 1084.559 us; speedup vs baseline: 1.3719x; 1.3719x over previous
//
#include <hip/hip_runtime.h>
#include <stdint.h>

typedef __bf16 bf16_t;
typedef _Float16 fp16_t;
typedef bf16_t bf16x8 __attribute__((ext_vector_type(8)));
typedef fp16_t fp16x4 __attribute__((ext_vector_type(4)));
typedef float f32x4 __attribute__((ext_vector_type(4)));

#define LOG2E 1.44269504088896340736f

__device__ __forceinline__ float sigm(float x) {
    return __builtin_amdgcn_rcpf(1.f + __builtin_amdgcn_exp2f(-LOG2E * x));
}
__device__ __forceinline__ float tanh_(float x) {
    return 1.f - 2.f * __builtin_amdgcn_rcpf(1.f + __builtin_amdgcn_exp2f((2.f * LOG2E) * x));
}

// ---------------------------------------------------------------------------
// Kernel 1: fold fuse_W2@fuse_W1 into a single 340-vector + scalar
// ---------------------------------------------------------------------------
__global__ void prep_fuse(const float* __restrict__ W1, const float* __restrict__ b1,
                          const float* __restrict__ W2, const float* __restrict__ b2,
                          float* __restrict__ v) {
    int u = threadIdx.x;
    if (u < 340) {
        float s = 0.f;
        for (int j = 0; j < 64; j++) s += W2[j] * W1[j * 340 + u];
        v[u] = s;
    } else if (u == 340) {
        float s = 0.f;
        for (int j = 0; j < 64; j++) s += W2[j] * b1[j];
        v[340] = s + b2[0];
    }
}

// ---------------------------------------------------------------------------
// Kernel 2: input GEMMs. BM=256, BN=128, BK=32, split-bf16 A.
// Output layout: [t][b][u][gate] fp16 (E: [t][b][col]); bias = b_ih + b_hh.
// ---------------------------------------------------------------------------
struct ModGemm {
    const float* x; const float* w; const float* bih; const float* bhh; fp16_t* xg;
    int D; int KB; int N4; int hshift;   // hshift: log2(H), 0 => direct col (E)
};
struct GemmArgs { ModGemm m[4]; int slot_mi[11]; int slot_nb[11]; };

__global__ __launch_bounds__(512) void gemm_all(GemmArgs ga) {
    __shared__ bf16_t sAh[256 * 40];
    __shared__ bf16_t sAl[256 * 40];
    __shared__ bf16_t sB[128 * 40];
    const int slot = blockIdx.y;
    const ModGemm mg = ga.m[ga.slot_mi[slot]];
    const int nb = ga.slot_nb[slot];
    const int ncol0 = nb << 7;
    const int tid = threadIdx.x;
    const int w = tid >> 6, l = tid & 63, lm = l & 15, q = l >> 4;
    const int wm = w & 3, wn = w >> 2;        // wave tile: 64 rows x 64 cols
    const int bm = blockIdx.x;
    const int D = mg.D, N4 = mg.N4;
    // staging assignments
    const int ra = tid >> 1, ca = (tid & 1) << 4;   // A: 2 thr/row, 16 cols
    const int rb = tid >> 2, cb = (tid & 3) << 3;   // B: 4 thr/row, 8 cols

    f32x4 acc[4][4];
#pragma unroll
    for (int a = 0; a < 4; a++)
#pragma unroll
        for (int b = 0; b < 4; b++) acc[a][b] = 0.f;

    for (int kb = 0; kb < mg.KB; kb++) {
        const int k0 = kb << 5;
        // ---- stage A (x): 256 x 32, hi/lo split
        {
            long grow = (long)(bm << 8) + ra;
            const float* src = mg.x + grow * D + k0 + ca;
            union { bf16_t e[16]; bf16x8 v[2]; } uh, ul;
            if (k0 + ca + 16 <= D) {
#pragma unroll
                for (int j = 0; j < 16; j += 2) {
                    float2 f = *(const float2*)(src + j);
                    bf16_t h0 = (bf16_t)f.x, h1 = (bf16_t)f.y;
                    uh.e[j] = h0; uh.e[j + 1] = h1;
                    ul.e[j] = (bf16_t)(f.x - (float)h0);
                    ul.e[j + 1] = (bf16_t)(f.y - (float)h1);
                }
            } else {
#pragma unroll
                for (int j = 0; j < 16; j++) {
                    int k = k0 + ca + j;
                    float fv = (k < D) ? mg.x[grow * D + k] : 0.f;
                    bf16_t h0 = (bf16_t)fv;
                    uh.e[j] = h0; ul.e[j] = (bf16_t)(fv - (float)h0);
                }
            }
            *(bf16x8*)&sAh[ra * 40 + ca] = uh.v[0];
            *(bf16x8*)&sAh[ra * 40 + ca + 8] = uh.v[1];
            *(bf16x8*)&sAl[ra * 40 + ca] = ul.v[0];
            *(bf16x8*)&sAl[ra * 40 + ca + 8] = ul.v[1];
        }
        // ---- stage B (W_ih strip): 128 x 32
        {
            int wrow = ncol0 + rb;
            bool vr = wrow < N4;
            const float* src = mg.w + (long)wrow * D + k0 + cb;
            union { bf16_t e[8]; bf16x8 v; } ub;
            if (vr && (k0 + cb + 8 <= D)) {
#pragma unroll
                for (int j = 0; j < 8; j += 2) {
                    float2 f = *(const float2*)(src + j);
                    ub.e[j] = (bf16_t)f.x; ub.e[j + 1] = (bf16_t)f.y;
                }
            } else {
#pragma unroll
                for (int j = 0; j < 8; j++) {
                    int k = k0 + cb + j;
                    ub.e[j] = (vr && k < D) ? (bf16_t)mg.w[(long)wrow * D + k] : (bf16_t)0.f;
                }
            }
            *(bf16x8*)&sB[rb * 40 + cb] = ub.v;
        }
        __syncthreads();
        bf16x8 ah[4], al[4];
#pragma unroll
        for (int mt = 0; mt < 4; mt++) {
            int row = (wm << 6) + (mt << 4) + lm;
            ah[mt] = *(const bf16x8*)&sAh[row * 40 + (q << 3)];
            al[mt] = *(const bf16x8*)&sAl[row * 40 + (q << 3)];
        }
#pragma unroll
        for (int nt = 0; nt < 4; nt++) {
            bf16x8 bfv = *(const bf16x8*)&sB[((wn << 6) + (nt << 4) + lm) * 40 + (q << 3)];
#pragma unroll
            for (int mt = 0; mt < 4; mt++) {
                acc[mt][nt] = __builtin_amdgcn_mfma_f32_16x16x32_bf16(ah[mt], bfv, acc[mt][nt], 0, 0, 0);
                acc[mt][nt] = __builtin_amdgcn_mfma_f32_16x16x32_bf16(al[mt], bfv, acc[mt][nt], 0, 0, 0);
            }
        }
        __syncthreads();
    }
    // ---- epilogue: +(b_ih+b_hh), store fp16 gate-interleaved
#pragma unroll
    for (int nt = 0; nt < 4; nt++) {
        int col = ncol0 + (wn << 6) + (nt << 4) + lm;
        if (col >= N4) continue;
        float bias = mg.bih[col] + mg.bhh[col];
        int colout = mg.hshift ? ((col & ((1 << mg.hshift) - 1)) << 2) | (col >> mg.hshift) : col;
#pragma unroll
        for (int mt = 0; mt < 4; mt++) {
#pragma unroll
            for (int r = 0; r < 4; r++) {
                long row = (long)(bm << 8) + (wm << 6) + (mt << 4) + (q << 2) + r;
                int b = (int)(row >> 9), t = (int)(row & 511);
                size_t dst = ((size_t)(t << 6) + b) * N4 + colout;
                mg.xg[dst] = (fp16_t)(acc[mt][nt][r] + bias);
            }
        }
    }
}

// ---------------------------------------------------------------------------
// Kernel 3: recurrent scan. 16 blocks = 4 mods x 4 batch-groups of 16.
// xg prefetched 4 steps ahead in registers; single barrier/step (dbuf h).
// ---------------------------------------------------------------------------
struct ModRec {
    const float* whh; const int* present; const fp16_t* xg;
    int N4; int voff;
};
struct RecArgs {
    ModRec m[4];
    const float* vvec;
    float* s_out;   // [4 mods][8 waves][64 b][512 t]
};

template <int H>
__device__ __forceinline__ void rec_step(
    int t, bool act, int w, int lm, int q, int b0,
    const bf16x8 (&wf)[4][H / 32], float vv,
    fp16x4 (&xvs)[4], const fp16_t* const (&px)[4], size_t tstride,
    float (&h_st)[4], float (&c_st)[4],
    const float* __restrict__ presf, const bf16_t* __restrict__ hbR,
    bf16_t* __restrict__ hbW, float* __restrict__ s_out) {
    constexpr int KT = H / 32, Hp = H + 8;
    if (act) {
        bf16x8 af[KT];
#pragma unroll
        for (int kt = 0; kt < KT; kt++)
            af[kt] = *(const bf16x8*)&hbR[lm * Hp + (kt << 5) + (q << 3)];
        f32x4 accv[4];
#pragma unroll
        for (int g = 0; g < 4; g++)
#pragma unroll
            for (int r = 0; r < 4; r++)
                accv[g][r] = (float)xvs[r][g];
        int tn = t + 4;
        if (tn < 512) {
#pragma unroll
            for (int r = 0; r < 4; r++)
                xvs[r] = *(const fp16x4*)(px[r] + (size_t)tn * tstride);
        }
#pragma unroll
        for (int kt = 0; kt < KT; kt++)
#pragma unroll
            for (int g = 0; g < 4; g++)
                accv[g] = __builtin_amdgcn_mfma_f32_16x16x32_bf16(af[kt], wf[g][kt], accv[g], 0, 0, 0);
        float cr[4];
#pragma unroll
        for (int r = 0; r < 4; r++) {
            float gi = sigm(accv[0][r]);
            float gf = sigm(accv[1][r]);
            float gg = tanh_(accv[2][r]);
            float go = sigm(accv[3][r]);
            float cn = gf * c_st[r] + gi * gg;
            float hn = go * tanh_(cn);
            float p = presf[(((q << 2) + r) << 9) + t];
            bool pb = (p != 0.f);
            h_st[r] = pb ? hn : h_st[r];
            c_st[r] = pb ? cn : c_st[r];
            cr[r] = h_st[r] * vv;
        }
        const int u = (w << 4) + lm;
#pragma unroll
        for (int r = 0; r < 4; r++)
            hbW[((q << 2) + r) * Hp + u] = (bf16_t)h_st[r];
#pragma unroll
        for (int r = 0; r < 4; r++) {
            cr[r] += __shfl_xor(cr[r], 1);
            cr[r] += __shfl_xor(cr[r], 2);
            cr[r] += __shfl_xor(cr[r], 4);
            cr[r] += __shfl_xor(cr[r], 8);
        }
        if (lm == 0) {
#pragma unroll
            for (int r = 0; r < 4; r++)
                s_out[(size_t)((w << 6) + b0 + (q << 2) + r) * 512 + t] = cr[r];
        }
    }
    __syncthreads();
}

template <int H>
__device__ void rec_mfma(const ModRec M, int grp, float* __restrict__ s_out,
                         const float* __restrict__ vvec,
                         float* presf, bf16_t* hb0, bf16_t* hb1, int tid) {
    constexpr int KT = H / 32, TPG = H / 16, Hp = H + 8;
    const int N4 = 4 * H;
    const int w = tid >> 6, l = tid & 63, lm = l & 15, q = l >> 4;
    const int b0 = grp << 4;
    const bool act = (w < TPG);

    for (int i = tid; i < 16 * Hp; i += 512) { hb0[i] = (bf16_t)0.f; hb1[i] = (bf16_t)0.f; }
    for (int i = tid; i < 16 * 512; i += 512)
        presf[i] = (float)M.present[((b0 + (i >> 9)) << 9) + (i & 511)];

    bf16x8 wf[4][KT];
    float vv = 0.f;
    const int u = (w << 4) + lm;
    if (act) {
#pragma unroll
        for (int g = 0; g < 4; g++) {
            int n = g * H + u;
#pragma unroll
            for (int kt = 0; kt < KT; kt++) {
                int k = (kt << 5) + (q << 3);
                const float* sp_ = M.whh + (long)n * H + k;
                float4 f0 = *(const float4*)sp_;
                float4 f1 = *(const float4*)(sp_ + 4);
                union { bf16_t e[8]; bf16x8 v; } uu;
                uu.e[0] = (bf16_t)f0.x; uu.e[1] = (bf16_t)f0.y;
                uu.e[2] = (bf16_t)f0.z; uu.e[3] = (bf16_t)f0.w;
                uu.e[4] = (bf16_t)f1.x; uu.e[5] = (bf16_t)f1.y;
                uu.e[6] = (bf16_t)f1.z; uu.e[7] = (bf16_t)f1.w;
                wf[g][kt] = uu.v;
            }
        }
        vv = vvec[M.voff + u];
    }
    const fp16_t* px[4];
#pragma unroll
    for (int r = 0; r < 4; r++)
        px[r] = M.xg + (size_t)(b0 + (q << 2) + r) * N4 + (u << 2);
    const size_t tstride = (size_t)64 * N4;

    fp16x4 xv[4][4];   // [slot][r]
    if (act) {
#pragma unroll
        for (int s = 0; s < 4; s++)
#pragma unroll
            for (int r = 0; r < 4; r++)
                xv[s][r] = *(const fp16x4*)(px[r] + (size_t)s * tstride);
    }
    float h_st[4] = {0, 0, 0, 0}, c_st[4] = {0, 0, 0, 0};
    __syncthreads();

    for (int t0 = 0; t0 < 512; t0 += 4) {
        rec_step<H>(t0 + 0, act, w, lm, q, b0, wf, vv, xv[0], px, tstride, h_st, c_st, presf, hb0, hb1, s_out);
        rec_step<H>(t0 + 1, act, w, lm, q, b0, wf, vv, xv[1], px, tstride, h_st, c_st, presf, hb1, hb0, s_out);
        rec_step<H>(t0 + 2, act, w, lm, q, b0, wf, vv, xv[2], px, tstride, h_st, c_st, presf, hb0, hb1, s_out);
        rec_step<H>(t0 + 3, act, w, lm, q, b0, wf, vv, xv[3], px, tstride, h_st, c_st, presf, hb1, hb0, s_out);
    }
}

// Emotient (H=20): fp32 VALU path, weights in registers, prefetch dist 4.
__device__ void rec_emot(const ModRec M, int grp, float* __restrict__ s_out,
                         const float* __restrict__ vvec,
                         float* presf, float* gbuf /*16*81*/, float* he /*16*21*/, int tid) {
    const int b0 = grp << 4;
    for (int i = tid; i < 16 * 21; i += 512) he[i] = 0.f;
    for (int i = tid; i < 16 * 512; i += 512)
        presf[i] = (float)M.present[((b0 + (i >> 9)) << 9) + (i & 511)];
    const int bl = tid >> 5;       // 0..15
    const int j0 = tid & 31;
    const bool has2 = (j0 < 16);
    float wr0[20], wr1[20], wr2[20];
#pragma unroll
    for (int k = 0; k < 20; k++) {
        wr0[k] = M.whh[j0 * 20 + k];
        wr1[k] = M.whh[(j0 + 32) * 20 + k];
        wr2[k] = has2 ? M.whh[(j0 + 64) * 20 + k] : 0.f;
    }
    const int b2 = tid / 20, u2 = tid % 20;
    const bool p2 = (tid < 320);
    float c_st = 0.f, h_st = 0.f;
    const fp16_t* px = M.xg + (size_t)(b0 + bl) * 80;   // + t*64*80
    fp16_t e0[4], e1[4], e2[4];
#pragma unroll
    for (int s = 0; s < 4; s++) {
        const fp16_t* p = px + (size_t)s * 5120;
        e0[s] = p[j0]; e1[s] = p[j0 + 32]; e2[s] = has2 ? p[j0 + 64] : (fp16_t)0.f;
    }
    __syncthreads();

    for (int t0 = 0; t0 < 512; t0 += 4) {
#pragma unroll
        for (int s = 0; s < 4; s++) {
            int t = t0 + s;
            float g0 = (float)e0[s];
            float g1 = (float)e1[s];
            float g2 = has2 ? (float)e2[s] : 0.f;
            int tn = t + 4;
            if (tn < 512) {
                const fp16_t* p = px + (size_t)tn * 5120;
                e0[s] = p[j0]; e1[s] = p[j0 + 32]; if (has2) e2[s] = p[j0 + 64];
            }
#pragma unroll
            for (int k = 0; k < 20; k++) {
                float hv = he[bl * 21 + k];
                g0 += wr0[k] * hv; g1 += wr1[k] * hv; g2 += wr2[k] * hv;
            }
            gbuf[bl * 81 + j0] = g0;
            gbuf[bl * 81 + j0 + 32] = g1;
            if (has2) gbuf[bl * 81 + j0 + 64] = g2;
            __syncthreads();
            if (p2) {
                float gi = sigm(gbuf[b2 * 81 + u2]);
                float gf = sigm(gbuf[b2 * 81 + u2 + 20]);
                float gg = tanh_(gbuf[b2 * 81 + u2 + 40]);
                float go = sigm(gbuf[b2 * 81 + u2 + 60]);
                float cn = gf * c_st + gi * gg;
                float hn = go * tanh_(cn);
                float p = presf[b2 * 512 + t];
                bool pb = (p != 0.f);
                h_st = pb ? hn : h_st;
                c_st = pb ? cn : c_st;
                he[b2 * 21 + u2] = h_st;
            }
            __syncthreads();
            if (tid < 16) {
                float ssum = 0.f;
#pragma unroll
                for (int uu = 0; uu < 20; uu++) ssum += he[tid * 21 + uu] * vvec[M.voff + uu];
                s_out[((b0 + tid) << 9) + t] = ssum;
            }
        }
    }
}

__global__ __launch_bounds__(512) void rec_all(RecArgs ra) {
    __shared__ float presf[16 * 512];     // 32 KB
    __shared__ bf16_t hb0[16 * 136];
    __shared__ bf16_t hb1[16 * 136];
    __shared__ float gbuf[16 * 81];
    __shared__ float he[16 * 21];
    const int tid = threadIdx.x;
    const int bid = blockIdx.x;
    const int mi = bid >> 2, grp = bid & 3;   // 0=L,1=E,2=A,3=I
    const ModRec M = ra.m[mi];
    float* s_out = ra.s_out + (size_t)mi * 8 * 64 * 512;
    if (mi == 1)      rec_emot(M, grp, s_out, ra.vvec, presf, gbuf, he, tid);
    else if (mi == 2) rec_mfma<64>(M, grp, s_out, ra.vvec, presf, hb0, hb1, tid);
    else              rec_mfma<128>(M, grp, s_out, ra.vvec, presf, hb0, hb1, tid);
}

// ---------------------------------------------------------------------------
// Kernel 4: out = mask * (sum of written partial slots + c0)
// slots: L:0-7, E:8, A:16-19, I:24-31
// ---------------------------------------------------------------------------
__global__ void fuse_out(const float* __restrict__ sp, const float* __restrict__ v,
                         const float* __restrict__ masks, float* __restrict__ out) {
    int i = threadIdx.x + blockIdx.x * 256;
    float c0 = v[340];
    float s = 0.f;
#pragma unroll
    for (int w = 0; w < 8; w++) s += sp[(size_t)w * 32768 + i];
    s += sp[(size_t)8 * 32768 + i];
#pragma unroll
    for (int w = 16; w < 20; w++) s += sp[(size_t)w * 32768 + i];
#pragma unroll
    for (int w = 24; w < 32; w++) s += sp[(size_t)w * 32768 + i];
    out[i] = masks[i] * (s + c0);
}

// ---------------------------------------------------------------------------
extern "C" void kernel_launch(void* const* d_in, const int* in_sizes, int n_in,
                              void* d_out, int out_size, void* d_ws, size_t ws_size,
                              hipStream_t stream) {
    const float* xL = (const float*)d_in[0];
    const int*   pL = (const int*)d_in[1];
    const float* WihL = (const float*)d_in[2];
    const float* WhhL = (const float*)d_in[3];
    const float* bihL = (const float*)d_in[4];
    const float* bhhL = (const float*)d_in[5];
    const float* xE = (const float*)d_in[6];
    const int*   pE = (const int*)d_in[7];
    const float* WihE = (const float*)d_in[8];
    const float* WhhE = (const float*)d_in[9];
    const float* bihE = (const float*)d_in[10];
    const float* bhhE = (const float*)d_in[11];
    const float* xA = (const float*)d_in[12];
    const int*   pA = (const int*)d_in[13];
    const float* WihA = (const float*)d_in[14];
    const float* WhhA = (const float*)d_in[15];
    const float* bihA = (const float*)d_in[16];
    const float* bhhA = (const float*)d_in[17];
    const float* xI = (const float*)d_in[18];
    const int*   pI = (const int*)d_in[19];
    const float* WihI = (const float*)d_in[20];
    const float* WhhI = (const float*)d_in[21];
    const float* bihI = (const float*)d_in[22];
    const float* bhhI = (const float*)d_in[23];
    const float* masks = (const float*)d_in[25];
    const float* fW1 = (const float*)d_in[26];
    const float* fb1 = (const float*)d_in[27];
    const float* fW2 = (const float*)d_in[28];
    const float* fb2 = (const float*)d_in[29];

    char* ws = (char*)d_ws;
    float* v     = (float*)ws;                           // 341 floats
    float* spart = (float*)(ws + (1 << 16));             // 32*32768 floats = 4 MB
    fp16_t* xgL = (fp16_t*)(ws + (1 << 16) + (4 << 20));
    fp16_t* xgE = xgL + (size_t)32768 * 512;
    fp16_t* xgA = xgE + (size_t)32768 * 80;
    fp16_t* xgI = xgA + (size_t)32768 * 256;

    prep_fuse<<<dim3(1), dim3(512), 0, stream>>>(fW1, fb1, fW2, fb2, v);

    GemmArgs ga;
    ga.m[0] = {xL, WihL, bihL, bhhL, xgL, 300,  10, 512, 7};
    ga.m[1] = {xE, WihE, bihE, bhhE, xgE, 30,   1,  80,  0};
    ga.m[2] = {xA, WihA, bihA, bhhA, xgA, 88,   3,  256, 6};
    ga.m[3] = {xI, WihI, bihI, bhhI, xgI, 1000, 32, 512, 7};
    const int mi_tab[11] = {0, 0, 0, 0, 3, 3, 3, 3, 2, 2, 1};
    const int nb_tab[11] = {0, 1, 2, 3, 0, 1, 2, 3, 0, 1, 0};
    for (int i = 0; i < 11; i++) { ga.slot_mi[i] = mi_tab[i]; ga.slot_nb[i] = nb_tab[i]; }
    gemm_all<<<dim3(128, 11), dim3(512), 0, stream>>>(ga);

    RecArgs ra;
    ra.m[0] = {WhhL, pL, xgL, 512, 0};
    ra.m[1] = {WhhE, pE, xgE, 80,  128};
    ra.m[2] = {WhhA, pA, xgA, 256, 148};
    ra.m[3] = {WhhI, pI, xgI, 512, 212};
    ra.vvec = v;
    ra.s_out = spart;
    rec_all<<<dim3(16), dim3(512), 0, stream>>>(ra);

    fuse_out<<<dim3(128), dim3(256), 0, stream>>>(spart, v, masks, (float*)d_out);
}